// Round 10
// baseline (57.383 us; speedup 1.0000x reference)
//
#include <hip/hip_runtime.h>

#define BROWS 524288
#define KBINS 64
#define GRID1 2048
// rows per block per outer iteration: 4 waves * 8 rows = 32 -> 8 iterations
#define ITERS (BROWS / (GRID1 * 32))

typedef float v4f __attribute__((ext_vector_type(4)));

// DPP row_shr add: val += lanes shifted right by n within each 16-lane row.
// bound_ctrl=1 -> out-of-range lanes contribute 0. Pure VALU (no LDS pipe).
#define DPP_ADD(val, ctrl)                                                 \
  do {                                                                     \
    int _s = __builtin_amdgcn_update_dpp(                                  \
        0, __builtin_bit_cast(int, (val)), (ctrl), 0xf, 0xf, true);        \
    (val) += __builtin_bit_cast(float, _s);                                \
  } while (0)
#define ROW_SHR1 0x111
#define ROW_SHR2 0x112
#define ROW_SHR4 0x114
#define ROW_SHR8 0x118

// Single kernel. Count stores: aligned shifted-window, nontemporal (r9).
// Loss: per-block partial -> packed fixed-point u64 atomicAdd (block count in
// bits 52+, biased sum below). NO fences (r2/r3 poison was the release fence's
// L2 writeback, not the atomic). Row 0 skips out[0]; only the winner block
// writes the loss slot -> no cross-block store race.
__global__ __launch_bounds__(256) void surv_main(
    const float* __restrict__ inp, const float* __restrict__ yv,
    const int* __restrict__ ev, float* __restrict__ out,
    unsigned long long* __restrict__ acc64)
{
  const int tid  = threadIdx.x;
  const int lane = tid & 63;
  const int wave = tid >> 6;   // 0..3
  const int sub  = lane >> 4;  // row within 4-row group
  const int l16  = lane & 15;  // lane within row group

  const float A   = 2.8853900817779268f;   // 2*log2(e)  (logit scale, log2 domain)
  const float M2  = 0.28853900817779268f;  // 0.2*log2(e) (margin*scale, log2 domain)
  const float S0  = 0.018315638888734179f; // exp(-4)
  const float IS0 = 54.598150033144236f;   // exp(+4)
  const float LN2 = 0.6931471805599453f;

  float acc = 0.f;

  for (int it = 0; it < ITERS; ++it) {
    const int base = (it * GRID1 + blockIdx.x) * 32 + wave * 8;
    const int row0 = base + sub;
    const int row1 = base + 4 + sub;

    // hoist loads: both rows' y/e/x plus prev-row y/e (same cache lines)
    const int rp0 = row0 ? row0 - 1 : 0;   // clamp only hit at global row 0
    const int rp1 = row1 - 1;
    const float y0 = yv[row0], y1 = yv[row1];
    const int   e0 = ev[row0], e1 = ev[row1];
    const float yp0 = yv[rp0], yp1 = yv[rp1];
    const int   ep0 = ev[rp0], ep1 = ev[rp1];
    const float4 x0 = *reinterpret_cast<const float4*>(
        inp + (size_t)row0 * KBINS + l16 * 4);
    const float4 x1 = *reinterpret_cast<const float4*>(
        inp + (size_t)row1 * KBINS + l16 * 4);

    #pragma unroll
    for (int h = 0; h < 2; ++h) {
      const int   row = h ? row1 : row0;
      const float y   = h ? y1 : y0;
      const int   e   = h ? e1 : e0;
      const float yp  = h ? yp1 : yp0;
      const int   ep  = h ? ep1 : ep0;
      const float4 x  = h ? x1 : x0;

      const int   b = (int)y;
      const bool valid = (y >= 0.f) && (y < 64.f);
      const int b_eff = valid ? b : 127;              // sentinel: c==0 everywhere
      const int hi    = (e != 0) ? b_eff : 63;        // count = [b_eff, hi]
      const bool all1 = (e == 0) && (b_eff == 0);     // count all-ones -> min==1
      const float m_in = all1 ? M2 : 0.f;             // margin on count==1 bins

      // prev row's bin-63 count: 1 iff (e!=0 && b==63) or (e==0 && valid)
      const int   bp = (int)yp;
      const bool  vp = (yp >= 0.f) && (yp < 64.f);
      const float c63p = (ep != 0) ? ((vp && bp == 63) ? 1.f : 0.f)
                                   : (vp ? 1.f : 0.f);

      const float xa[4] = {x.x, x.y, x.z, x.w};
      float correct = 0.f, fev = 0.f, fcs = 0.f;
      float c[4];
      #pragma unroll
      for (int j = 0; j < 4; ++j) {
        const int bin = l16 * 4 + j;
        const bool cb = (bin >= b_eff) && (bin <= hi);
        const float mm = cb ? m_in : M2;
        const float t  = fmaf(xa[j], A, mm);           // log2-domain logit
        const float pen = __builtin_amdgcn_exp2f(t);   // exp(+logit)
        const float pe  = __builtin_amdgcn_exp2f(-t);  // exp(-logit)
        correct += cb ? pe  : 0.f;
        fcs     += cb ? 0.f : pe;
        fev     += cb ? 0.f : pen;
        c[j] = cb ? 1.f : 0.f;
      }

      // aligned shifted-window nontemporal store: lane covers count bins
      // l16*4-1 .. l16*4+2 (cv[0] at l16==0 = prev row's bin 63).
      // Row 0 lane 0 skips out[0] (loss slot, written only by the winner).
      {
        const int  binm1 = l16 * 4 - 1;
        const bool cm1 = (binm1 >= b_eff) && (binm1 <= hi);
        v4f cv;
        cv[0] = (l16 == 0) ? c63p : (cm1 ? 1.f : 0.f);
        cv[1] = c[0]; cv[2] = c[1]; cv[3] = c[2];
        float* dst = out + (size_t)row * KBINS + l16 * 4;
        if (row == 0 && l16 == 0) {
          __builtin_nontemporal_store(cv[1], out + 1);
          __builtin_nontemporal_store(cv[2], out + 2);
          __builtin_nontemporal_store(cv[3], out + 3);
        } else {
          __builtin_nontemporal_store(cv, reinterpret_cast<v4f*>(dst));
        }
        if (row == BROWS - 1 && l16 == 15)
          __builtin_nontemporal_store(c[3], out + (size_t)BROWS * KBINS);
      }

      // 16-lane reduction on the VALU pipe via DPP row_shr; sum -> lane 15
      DPP_ADD(correct, ROW_SHR1); DPP_ADD(fev, ROW_SHR1); DPP_ADD(fcs, ROW_SHR1);
      DPP_ADD(correct, ROW_SHR2); DPP_ADD(fev, ROW_SHR2); DPP_ADD(fcs, ROW_SHR2);
      DPP_ADD(correct, ROW_SHR4); DPP_ADD(fev, ROW_SHR4); DPP_ADD(fcs, ROW_SHR4);
      DPP_ADD(correct, ROW_SHR8); DPP_ADD(fev, ROW_SHR8); DPP_ADD(fcs, ROW_SHR8);

      // sum(count)==1  <=>  valid && (event || b==K-1)
      const bool is_event = valid && (e != 0 || b == KBINS - 1);
      // lev: log(a)+log(b) = LN2*log2(a*b) -> one transcendental
      const float lev = __builtin_amdgcn_logf((correct + S0) * (fev + S0)) * LN2;
      const float lcs = __builtin_amdgcn_logf(
                            fmaf(fcs, IS0, fmaf(correct, fcs, 1.f))) * LN2;
      if (l16 == 15) acc += is_event ? lev : lcs;      // owner = lane 15 (DPP)
    }
  }

  // block reduction: acc nonzero at lanes {15,31,47,63}
  acc += __shfl_xor(acc, 16, 64);
  acc += __shfl_xor(acc, 32, 64);
  __shared__ float sm[4];
  if (lane == 15) sm[wave] = acc;
  __syncthreads();
  if (tid == 0) {
    const float partial = (sm[0] + sm[1]) + (sm[2] + sm[3]);
    // per-sample loss in [-8, ~40] -> partial in [-2048, ~10300]; bias 2100
    // keeps fx >= 0. Scale 2^18: total < 2048 * 2^32 << 2^52 -> the block
    // count in bits 52+ never sees a carry.
    const unsigned long long fx =
        (unsigned long long)(((double)partial + 2100.0) * 262144.0 + 0.5);
    const unsigned long long mine = (1ULL << 52) + fx;
    const unsigned long long old  = atomicAdd(acc64, mine);
    const unsigned long long tot  = old + mine;
    if ((tot >> 52) == (unsigned long long)GRID1) {
      const double s = (double)(tot & ((1ULL << 52) - 1)) * (1.0 / 262144.0)
                     - 2100.0 * (double)GRID1;
      out[0] = (float)(s / (double)BROWS);
    }
  }
}

extern "C" void kernel_launch(void* const* d_in, const int* in_sizes, int n_in,
                              void* d_out, int out_size, void* d_ws, size_t ws_size,
                              hipStream_t stream) {
  const float* inp = (const float*)d_in[0];
  const float* y   = (const float*)d_in[1];
  const int*   e   = (const int*)d_in[2];
  float* out = (float*)d_out;
  unsigned long long* acc64 = (unsigned long long*)d_ws;

  hipMemsetAsync(acc64, 0, sizeof(unsigned long long), stream);
  surv_main<<<GRID1, 256, 0, stream>>>(inp, y, e, out, acc64);
}

// Round 11
// 47.500 us; speedup vs baseline: 1.2081x; 1.2081x over previous
//
#include <hip/hip_runtime.h>

#define BROWS 524288
#define KBINS 64
#define GRID1 2048
// rows per block per outer iteration: 4 waves * 8 rows = 32 -> 8 iterations
#define ITERS (BROWS / (GRID1 * 32))

typedef float v4f __attribute__((ext_vector_type(4)));

// DPP row_shr add: val += lanes shifted right by n within each 16-lane row.
// bound_ctrl=1 -> out-of-range lanes contribute 0. Pure VALU (no LDS pipe).
#define DPP_ADD(val, ctrl)                                                 \
  do {                                                                     \
    int _s = __builtin_amdgcn_update_dpp(                                  \
        0, __builtin_bit_cast(int, (val)), (ctrl), 0xf, 0xf, true);        \
    (val) += __builtin_bit_cast(float, _s);                                \
  } while (0)
#define ROW_SHR1 0x111
#define ROW_SHR2 0x112
#define ROW_SHR4 0x114
#define ROW_SHR8 0x118

__global__ __launch_bounds__(256) void surv_main(
    const float* __restrict__ inp, const float* __restrict__ yv,
    const int* __restrict__ ev, float* __restrict__ out,
    float* __restrict__ partials)
{
  const int tid  = threadIdx.x;
  const int lane = tid & 63;
  const int wave = tid >> 6;   // 0..3
  const int sub  = lane >> 4;  // row within 4-row group
  const int l16  = lane & 15;  // lane within row group

  const float A   = 2.8853900817779268f;   // 2*log2(e)  (logit scale, log2 domain)
  const float M2  = 0.28853900817779268f;  // 0.2*log2(e) (margin*scale, log2 domain)
  const float S0  = 0.018315638888734179f; // exp(-4)
  const float IS0 = 54.598150033144236f;   // exp(+4)
  const float LN2 = 0.6931471805599453f;

  float acc = 0.f;

  for (int it = 0; it < ITERS; ++it) {
    const int base = (it * GRID1 + blockIdx.x) * 32 + wave * 8;
    const int row0 = base + sub;
    const int row1 = base + 4 + sub;

    // hoist loads: both rows' y/e/x plus prev-row y/e (same cache lines)
    const int rp0 = row0 ? row0 - 1 : 0;   // clamp only hit at global row 0
    const int rp1 = row1 - 1;
    const float y0 = yv[row0], y1 = yv[row1];
    const int   e0 = ev[row0], e1 = ev[row1];
    const float yp0 = yv[rp0], yp1 = yv[rp1];
    const int   ep0 = ev[rp0], ep1 = ev[rp1];
    const float4 x0 = *reinterpret_cast<const float4*>(
        inp + (size_t)row0 * KBINS + l16 * 4);
    const float4 x1 = *reinterpret_cast<const float4*>(
        inp + (size_t)row1 * KBINS + l16 * 4);

    #pragma unroll
    for (int h = 0; h < 2; ++h) {
      const int   row = h ? row1 : row0;
      const float y   = h ? y1 : y0;
      const int   e   = h ? e1 : e0;
      const float yp  = h ? yp1 : yp0;
      const int   ep  = h ? ep1 : ep0;
      const float4 x  = h ? x1 : x0;

      const int   b = (int)y;
      const bool valid = (y >= 0.f) && (y < 64.f);
      const int b_eff = valid ? b : 127;              // sentinel: c==0 everywhere
      const int hi    = (e != 0) ? b_eff : 63;        // count = [b_eff, hi]
      const bool all1 = (e == 0) && (b_eff == 0);     // count all-ones -> min==1
      const float m_in = all1 ? M2 : 0.f;             // margin on count==1 bins

      // prev row's bin-63 count: 1 iff (e!=0 && b==63) or (e==0 && valid)
      const int   bp = (int)yp;
      const bool  vp = (yp >= 0.f) && (yp < 64.f);
      const float c63p = (ep != 0) ? ((vp && bp == 63) ? 1.f : 0.f)
                                   : (vp ? 1.f : 0.f);

      const float xa[4] = {x.x, x.y, x.z, x.w};
      float correct = 0.f, fev = 0.f, fcs = 0.f;
      float c[4];
      #pragma unroll
      for (int j = 0; j < 4; ++j) {
        const int bin = l16 * 4 + j;
        const bool cb = (bin >= b_eff) && (bin <= hi);
        const float mm = cb ? m_in : M2;
        const float t  = fmaf(xa[j], A, mm);           // log2-domain logit
        const float pen = __builtin_amdgcn_exp2f(t);   // exp(+logit)
        const float pe  = __builtin_amdgcn_exp2f(-t);  // exp(-logit)
        correct += cb ? pe  : 0.f;
        fcs     += cb ? 0.f : pe;
        fev     += cb ? 0.f : pen;
        c[j] = cb ? 1.f : 0.f;
      }

      // aligned shifted-window store, NONTEMPORAL: write-once/never-read
      // stream bypasses L2/L3; each wave's store = 1024B line-aligned
      // contiguous -> perfect write combining. Lane covers count bins
      // l16*4-1 .. l16*4+2 (cv[0] at l16==0 = prev row's bin 63). out[0]
      // gets garbage, overwritten by surv_reduce afterwards.
      {
        const int  binm1 = l16 * 4 - 1;
        const bool cm1 = (binm1 >= b_eff) && (binm1 <= hi);
        v4f cv;
        cv[0] = (l16 == 0) ? c63p : (cm1 ? 1.f : 0.f);
        cv[1] = c[0]; cv[2] = c[1]; cv[3] = c[2];
        __builtin_nontemporal_store(
            cv, reinterpret_cast<v4f*>(out + (size_t)row * KBINS + l16 * 4));
        if (row == BROWS - 1 && l16 == 15)
          __builtin_nontemporal_store(c[3], out + (size_t)BROWS * KBINS);
      }

      // 16-lane reduction on the VALU pipe via DPP row_shr; sum -> lane 15
      DPP_ADD(correct, ROW_SHR1); DPP_ADD(fev, ROW_SHR1); DPP_ADD(fcs, ROW_SHR1);
      DPP_ADD(correct, ROW_SHR2); DPP_ADD(fev, ROW_SHR2); DPP_ADD(fcs, ROW_SHR2);
      DPP_ADD(correct, ROW_SHR4); DPP_ADD(fev, ROW_SHR4); DPP_ADD(fcs, ROW_SHR4);
      DPP_ADD(correct, ROW_SHR8); DPP_ADD(fev, ROW_SHR8); DPP_ADD(fcs, ROW_SHR8);

      // sum(count)==1  <=>  valid && (event || b==K-1)
      const bool is_event = valid && (e != 0 || b == KBINS - 1);
      // lev: log(a)+log(b) = LN2*log2(a*b) -> one transcendental
      const float lev = __builtin_amdgcn_logf((correct + S0) * (fev + S0)) * LN2;
      const float lcs = __builtin_amdgcn_logf(
                            fmaf(fcs, IS0, fmaf(correct, fcs, 1.f))) * LN2;
      if (l16 == 15) acc += is_event ? lev : lcs;      // owner = lane 15 (DPP)
    }
  }

  // block reduction: acc nonzero at lanes {15,31,47,63}
  acc += __shfl_xor(acc, 16, 64);
  acc += __shfl_xor(acc, 32, 64);
  __shared__ float sm[4];
  if (lane == 15) sm[wave] = acc;
  __syncthreads();
  if (tid == 0) partials[blockIdx.x] = (sm[0] + sm[1]) + (sm[2] + sm[3]);
}

__global__ __launch_bounds__(256) void surv_reduce(
    const float* __restrict__ partials, float* __restrict__ out)
{
  __shared__ float sm[256];
  float s = 0.f;
  for (int i = threadIdx.x; i < GRID1; i += 256) s += partials[i];
  sm[threadIdx.x] = s;
  __syncthreads();
  for (int o = 128; o > 0; o >>= 1) {
    if (threadIdx.x < o) sm[threadIdx.x] += sm[threadIdx.x + o];
    __syncthreads();
  }
  if (threadIdx.x == 0) out[0] = sm[0] * (1.0f / (float)BROWS);
}

extern "C" void kernel_launch(void* const* d_in, const int* in_sizes, int n_in,
                              void* d_out, int out_size, void* d_ws, size_t ws_size,
                              hipStream_t stream) {
  const float* inp = (const float*)d_in[0];
  const float* y   = (const float*)d_in[1];
  const int*   e   = (const int*)d_in[2];
  float* out      = (float*)d_out;
  float* partials = (float*)d_ws;   // GRID1 floats

  surv_main<<<GRID1, 256, 0, stream>>>(inp, y, e, out, partials);
  surv_reduce<<<1, 256, 0, stream>>>(partials, out);
}